// Round 1
// baseline (1064.592 us; speedup 1.0000x reference)
//
#include <hip/hip_runtime.h>
#include <hip/hip_bf16.h>

#define NB 8
#define CH 256
#define DQ 128
#define NE 256
#define NN 4096

using bf16x8 = __attribute__((ext_vector_type(8))) __bf16;
using f32x4  = __attribute__((ext_vector_type(4))) float;

__device__ __forceinline__ bf16x8 pack_w(const float* __restrict__ wp){
  float4 w0 = *(const float4*)wp;
  float4 w1 = *(const float4*)(wp + 4);
  bf16x8 r;
  r[0]=(__bf16)w0.x; r[1]=(__bf16)w0.y; r[2]=(__bf16)w0.z; r[3]=(__bf16)w0.w;
  r[4]=(__bf16)w1.x; r[5]=(__bf16)w1.y; r[6]=(__bf16)w1.z; r[7]=(__bf16)w1.w;
  return r;
}

// ---------------------------------------------------------------- proj Q ----
// Q[b][n][d] = (yf . Wq^T + bq) * scale   (scale folded into stored Q)
__global__ __launch_bounds__(256) void proj_q_k(
    const float* __restrict__ y, const float* __restrict__ Wq,
    const float* __restrict__ bq, __bf16* __restrict__ Q)
{
  const int b    = blockIdx.y;
  const int w    = threadIdx.x >> 6;
  const int lane = threadIdx.x & 63;
  const int cq   = lane & 15, g = lane >> 4;
  const int n0   = blockIdx.x * 64 + w * 16;
  const float scale = 0.08838834764831845f;  // 1/sqrt(128)

  f32x4 acc[8] = {};
  const float* yb = y + (size_t)b * CH * NN;
#pragma unroll
  for (int kc = 0; kc < 8; ++kc) {
    const int kb = kc * 32 + g * 8;
    bf16x8 af;
#pragma unroll
    for (int s = 0; s < 8; ++s)
      af[s] = (__bf16)yb[(size_t)(kb + s) * NN + n0 + cq];
#pragma unroll
    for (int ct = 0; ct < 8; ++ct) {
      bf16x8 bfr = pack_w(Wq + (ct * 16 + cq) * CH + kb);
      acc[ct] = __builtin_amdgcn_mfma_f32_16x16x32_bf16(af, bfr, acc[ct], 0, 0, 0);
    }
  }
#pragma unroll
  for (int ct = 0; ct < 8; ++ct) {
    const int col = ct * 16 + cq;
    const float bias = bq[col];
#pragma unroll
    for (int r = 0; r < 4; ++r) {
      const int n = n0 + g * 4 + r;
      Q[((size_t)b * NN + n) * DQ + col] = (__bf16)((acc[ct][r] + bias) * scale);
    }
  }
}

// --------------------------------------------------------------- proj KV ----
// K[b][n][d] = xf.Wk^T + bk ;  Vt[b][e][n] = (xf.Wv^T + bv)^T  (V transposed)
__global__ __launch_bounds__(256) void proj_kv_k(
    const float* __restrict__ x,
    const float* __restrict__ Wk, const float* __restrict__ bk,
    const float* __restrict__ Wv, const float* __restrict__ bv,
    __bf16* __restrict__ K, __bf16* __restrict__ Vt)
{
  const int b    = blockIdx.y;
  const int w    = threadIdx.x >> 6;
  const int lane = threadIdx.x & 63;
  const int cq   = lane & 15, g = lane >> 4;
  const int n0   = blockIdx.x * 64 + w * 16;

  f32x4 acc[24] = {};
  const float* xb = x + (size_t)b * CH * NN;
#pragma unroll
  for (int kc = 0; kc < 8; ++kc) {
    const int kb = kc * 32 + g * 8;
    bf16x8 af;
#pragma unroll
    for (int s = 0; s < 8; ++s)
      af[s] = (__bf16)xb[(size_t)(kb + s) * NN + n0 + cq];
#pragma unroll
    for (int ct = 0; ct < 24; ++ct) {
      const float* wbase = (ct < 8) ? (Wk + (ct * 16 + cq) * CH)
                                    : (Wv + ((ct - 8) * 16 + cq) * CH);
      bf16x8 bfr = pack_w(wbase + kb);
      acc[ct] = __builtin_amdgcn_mfma_f32_16x16x32_bf16(af, bfr, acc[ct], 0, 0, 0);
    }
  }
#pragma unroll
  for (int ct = 0; ct < 8; ++ct) {
    const int col = ct * 16 + cq;
    const float bias = bk[col];
#pragma unroll
    for (int r = 0; r < 4; ++r) {
      const int n = n0 + g * 4 + r;
      K[((size_t)b * NN + n) * DQ + col] = (__bf16)(acc[ct][r] + bias);
    }
  }
#pragma unroll
  for (int ct = 8; ct < 24; ++ct) {
    const int e = (ct - 8) * 16 + cq;
    const float bias = bv[e];
#pragma unroll
    for (int r = 0; r < 4; ++r) {
      const int n = n0 + g * 4 + r;
      Vt[((size_t)b * NE + e) * NN + n] = (__bf16)(acc[ct][r] + bias);
    }
  }
}

// ------------------------------------------------------------- attention ----
// flash-style: each wave owns 16 q rows; KV tiles of 64; online softmax.
__global__ __launch_bounds__(256) void attn_k(
    const __bf16* __restrict__ Q, const __bf16* __restrict__ K,
    const __bf16* __restrict__ Vt, __bf16* __restrict__ H)
{
  __shared__ __bf16 P[4][16][72];   // per-wave P tile, +8 pad
  const int b    = blockIdx.y;
  const int w    = threadIdx.x >> 6;
  const int lane = threadIdx.x & 63;
  const int cq   = lane & 15, g = lane >> 4;
  const int n0   = blockIdx.x * 64 + w * 16;

  bf16x8 qf[4];
  const __bf16* Qb = Q + ((size_t)b * NN + n0 + cq) * DQ + g * 8;
#pragma unroll
  for (int kc = 0; kc < 4; ++kc) qf[kc] = *(const bf16x8*)(Qb + kc * 32);

  float m[4] = {-1e30f, -1e30f, -1e30f, -1e30f};
  float l[4] = {};
  f32x4 h[16] = {};

  for (int kv0 = 0; kv0 < NN; kv0 += 64) {
    f32x4 s[4] = {};
#pragma unroll
    for (int kc = 0; kc < 4; ++kc) {
#pragma unroll
      for (int ct = 0; ct < 4; ++ct) {
        bf16x8 kf = *(const bf16x8*)(K + ((size_t)b * NN + kv0 + ct * 16 + cq) * DQ
                                       + kc * 32 + g * 8);
        s[ct] = __builtin_amdgcn_mfma_f32_16x16x32_bf16(qf[kc], kf, s[ct], 0, 0, 0);
      }
    }
    // online softmax — row r lives at reg r in lanes with same (lane>>4)
    float alpha[4];
#pragma unroll
    for (int r = 0; r < 4; ++r) {
      float mx = fmaxf(fmaxf(s[0][r], s[1][r]), fmaxf(s[2][r], s[3][r]));
      mx = fmaxf(mx, __shfl_xor(mx, 1));
      mx = fmaxf(mx, __shfl_xor(mx, 2));
      mx = fmaxf(mx, __shfl_xor(mx, 4));
      mx = fmaxf(mx, __shfl_xor(mx, 8));
      const float mn = fmaxf(m[r], mx);
      alpha[r] = __expf(m[r] - mn);
      m[r] = mn;
    }
    float rs[4] = {};
#pragma unroll
    for (int ct = 0; ct < 4; ++ct) {
#pragma unroll
      for (int r = 0; r < 4; ++r) {
        const float p = __expf(s[ct][r] - m[r]);
        P[w][g * 4 + r][ct * 16 + cq] = (__bf16)p;
        rs[r] += p;
      }
    }
#pragma unroll
    for (int r = 0; r < 4; ++r) {
      rs[r] += __shfl_xor(rs[r], 1);
      rs[r] += __shfl_xor(rs[r], 2);
      rs[r] += __shfl_xor(rs[r], 4);
      rs[r] += __shfl_xor(rs[r], 8);
      l[r] = l[r] * alpha[r] + rs[r];
    }
#pragma unroll
    for (int et = 0; et < 16; ++et) {
#pragma unroll
      for (int r = 0; r < 4; ++r) h[et][r] *= alpha[r];
    }
    // PV:  A = P (from LDS), B = V^T fragment straight from global Vt
#pragma unroll
    for (int kvc = 0; kvc < 2; ++kvc) {
      bf16x8 pf = *(const bf16x8*)(&P[w][cq][kvc * 32 + g * 8]);
#pragma unroll
      for (int et = 0; et < 16; ++et) {
        bf16x8 vf = *(const bf16x8*)(Vt + ((size_t)b * NE + et * 16 + cq) * NN
                                       + kv0 + kvc * 32 + g * 8);
        h[et] = __builtin_amdgcn_mfma_f32_16x16x32_bf16(pf, vf, h[et], 0, 0, 0);
      }
    }
  }
  float inv[4];
#pragma unroll
  for (int r = 0; r < 4; ++r) inv[r] = 1.0f / l[r];
#pragma unroll
  for (int et = 0; et < 16; ++et) {
#pragma unroll
    for (int r = 0; r < 4; ++r) {
      const int n = n0 + g * 4 + r;
      H[((size_t)b * NN + n) * NE + et * 16 + cq] = (__bf16)(h[et][r] * inv[r]);
    }
  }
}

// ------------------------------------------------------------ out proj ------
// out[b][f][n] = x[b][f][n] + H.Wo^T + bo
__global__ __launch_bounds__(256) void outproj_k(
    const __bf16* __restrict__ H, const float* __restrict__ Wo,
    const float* __restrict__ bo, const float* __restrict__ x,
    float* __restrict__ out)
{
  const int b    = blockIdx.y;
  const int w    = threadIdx.x >> 6;
  const int lane = threadIdx.x & 63;
  const int cq   = lane & 15, g = lane >> 4;
  const int n0   = blockIdx.x * 64 + w * 16;

  f32x4 acc[16] = {};
  const __bf16* Hb = H + ((size_t)b * NN + n0 + cq) * NE;
#pragma unroll
  for (int kc = 0; kc < 8; ++kc) {
    bf16x8 af = *(const bf16x8*)(Hb + kc * 32 + g * 8);
#pragma unroll
    for (int ct = 0; ct < 16; ++ct) {
      bf16x8 bfr = pack_w(Wo + (ct * 16 + cq) * CH + kc * 32 + g * 8);
      acc[ct] = __builtin_amdgcn_mfma_f32_16x16x32_bf16(af, bfr, acc[ct], 0, 0, 0);
    }
  }
#pragma unroll
  for (int ct = 0; ct < 16; ++ct) {
    const int f = ct * 16 + cq;
    const float bias = bo[f];
#pragma unroll
    for (int r = 0; r < 4; ++r) {
      const int n = n0 + g * 4 + r;
      const size_t idx = ((size_t)b * CH + f) * NN + n;
      out[idx] = x[idx] + acc[ct][r] + bias;
    }
  }
}

// ----------------------------------------------------------------------------
extern "C" void kernel_launch(void* const* d_in, const int* in_sizes, int n_in,
                              void* d_out, int out_size, void* d_ws, size_t ws_size,
                              hipStream_t stream) {
  const float* x  = (const float*)d_in[0];
  const float* y  = (const float*)d_in[1];
  const float* Wq = (const float*)d_in[2];
  const float* bq = (const float*)d_in[3];
  const float* Wk = (const float*)d_in[4];
  const float* bk = (const float*)d_in[5];
  const float* Wv = (const float*)d_in[6];
  const float* bv = (const float*)d_in[7];
  const float* Wo = (const float*)d_in[8];
  const float* bo = (const float*)d_in[9];
  float* out = (float*)d_out;

  char* ws = (char*)d_ws;
  __bf16* Q  = (__bf16*)(ws);                       //  8 MB  [b][n][128]
  __bf16* K  = (__bf16*)(ws + (size_t)8  * 1024 * 1024);  //  8 MB  [b][n][128]
  __bf16* Vt = (__bf16*)(ws + (size_t)16 * 1024 * 1024);  // 16 MB  [b][e][n]
  __bf16* H  = (__bf16*)(ws + (size_t)32 * 1024 * 1024);  // 16 MB  [b][n][e]

  dim3 grid(64, 8), blk(256);
  proj_q_k <<<grid, blk, 0, stream>>>(y, Wq, bq, Q);
  proj_kv_k<<<grid, blk, 0, stream>>>(x, Wk, bk, Wv, bv, K, Vt);
  attn_k   <<<grid, blk, 0, stream>>>(Q, K, Vt, H);
  outproj_k<<<grid, blk, 0, stream>>>(H, Wo, bo, x, out);
}

// Round 2
// 667.507 us; speedup vs baseline: 1.5949x; 1.5949x over previous
//
#include <hip/hip_runtime.h>
#include <hip/hip_bf16.h>
#include <stdint.h>

#define NB 8
#define CH 256
#define DQ 128
#define NE 256
#define NN 4096

using bf16x8 = __attribute__((ext_vector_type(8))) __bf16;
using f32x4  = __attribute__((ext_vector_type(4))) float;

__device__ __forceinline__ void gl_lds16(const void* g, void* l){
  __builtin_amdgcn_global_load_lds(
      (const __attribute__((address_space(1))) unsigned int*)g,
      (__attribute__((address_space(3))) unsigned int*)l, 16, 0, 0);
}

__device__ __forceinline__ bf16x8 pack_w(const float* __restrict__ wp){
  float4 w0 = *(const float4*)wp;
  float4 w1 = *(const float4*)(wp + 4);
  bf16x8 r;
  r[0]=(__bf16)w0.x; r[1]=(__bf16)w0.y; r[2]=(__bf16)w0.z; r[3]=(__bf16)w0.w;
  r[4]=(__bf16)w1.x; r[5]=(__bf16)w1.y; r[6]=(__bf16)w1.z; r[7]=(__bf16)w1.w;
  return r;
}

// ---------------------------------------------------------------- proj Q ----
__global__ __launch_bounds__(256) void proj_q_k(
    const float* __restrict__ y, const float* __restrict__ Wq,
    const float* __restrict__ bq, __bf16* __restrict__ Q)
{
  const int b    = blockIdx.y;
  const int w    = threadIdx.x >> 6;
  const int lane = threadIdx.x & 63;
  const int cq   = lane & 15, g = lane >> 4;
  const int n0   = blockIdx.x * 64 + w * 16;
  const float scale = 0.08838834764831845f;  // 1/sqrt(128)

  f32x4 acc[8] = {};
  const float* yb = y + (size_t)b * CH * NN;
#pragma unroll
  for (int kc = 0; kc < 8; ++kc) {
    const int kb = kc * 32 + g * 8;
    bf16x8 af;
#pragma unroll
    for (int s = 0; s < 8; ++s)
      af[s] = (__bf16)yb[(size_t)(kb + s) * NN + n0 + cq];
#pragma unroll
    for (int ct = 0; ct < 8; ++ct) {
      bf16x8 bfr = pack_w(Wq + (ct * 16 + cq) * CH + kb);
      acc[ct] = __builtin_amdgcn_mfma_f32_16x16x32_bf16(af, bfr, acc[ct], 0, 0, 0);
    }
  }
#pragma unroll
  for (int ct = 0; ct < 8; ++ct) {
    const int col = ct * 16 + cq;
    const float bias = bq[col];
#pragma unroll
    for (int r = 0; r < 4; ++r) {
      const int n = n0 + g * 4 + r;
      Q[((size_t)b * NN + n) * DQ + col] = (__bf16)((acc[ct][r] + bias) * scale);
    }
  }
}

// --------------------------------------------------------------- proj KV ----
__global__ __launch_bounds__(256) void proj_kv_k(
    const float* __restrict__ x,
    const float* __restrict__ Wk, const float* __restrict__ bk,
    const float* __restrict__ Wv, const float* __restrict__ bv,
    __bf16* __restrict__ K, __bf16* __restrict__ Vt)
{
  const int b    = blockIdx.y;
  const int w    = threadIdx.x >> 6;
  const int lane = threadIdx.x & 63;
  const int cq   = lane & 15, g = lane >> 4;
  const int n0   = blockIdx.x * 64 + w * 16;

  f32x4 acc[24] = {};
  const float* xb = x + (size_t)b * CH * NN;
#pragma unroll
  for (int kc = 0; kc < 8; ++kc) {
    const int kb = kc * 32 + g * 8;
    bf16x8 af;
#pragma unroll
    for (int s = 0; s < 8; ++s)
      af[s] = (__bf16)xb[(size_t)(kb + s) * NN + n0 + cq];
#pragma unroll
    for (int ct = 0; ct < 24; ++ct) {
      const float* wbase = (ct < 8) ? (Wk + (ct * 16 + cq) * CH)
                                    : (Wv + ((ct - 8) * 16 + cq) * CH);
      bf16x8 bfr = pack_w(wbase + kb);
      acc[ct] = __builtin_amdgcn_mfma_f32_16x16x32_bf16(af, bfr, acc[ct], 0, 0, 0);
    }
  }
#pragma unroll
  for (int ct = 0; ct < 8; ++ct) {
    const int col = ct * 16 + cq;
    const float bias = bk[col];
#pragma unroll
    for (int r = 0; r < 4; ++r) {
      const int n = n0 + g * 4 + r;
      K[((size_t)b * NN + n) * DQ + col] = (__bf16)(acc[ct][r] + bias);
    }
  }
#pragma unroll
  for (int ct = 8; ct < 24; ++ct) {
    const int e = (ct - 8) * 16 + cq;
    const float bias = bv[e];
#pragma unroll
    for (int r = 0; r < 4; ++r) {
      const int n = n0 + g * 4 + r;
      Vt[((size_t)b * NE + e) * NN + n] = (__bf16)(acc[ct][r] + bias);
    }
  }
}

// ------------------------------------------------------------- attention ----
// flash-style, LDS-staged K/V (async global_load_lds, double buffer),
// 4 waves x 16 q-rows, KVBLK=32, optional kv-split with combine pass.
template<int KSPLIT>
__global__ __launch_bounds__(256) void attn2_k(
    const __bf16* __restrict__ Q, const __bf16* __restrict__ K,
    const __bf16* __restrict__ Vt, __bf16* __restrict__ Hout,
    float2* __restrict__ ml)
{
  __shared__ __bf16 Kt[2][32][128];   // [buf][kv][d]   16 KB
  __shared__ __bf16 Vs[2][256][32];   // [buf][e][kv]   32 KB
  __shared__ __bf16 P[4][16][32];     // [wave][q][kv]   4 KB

  const int tid  = threadIdx.x;
  const int w    = tid >> 6, lane = tid & 63;
  const int cq   = lane & 15, g = lane >> 4;
  const int b    = blockIdx.y;
  const int split = (KSPLIT == 2) ? blockIdx.z : 0;
  const int n0   = blockIdx.x * 64 + w * 16;
  const int kvbase = split * (NN / KSPLIT);
  const int nsteps = (NN / KSPLIT) / 32;

  const __bf16* Kb = K  + (size_t)b * NN * DQ;
  const __bf16* Vb = Vt + (size_t)b * NE * NN;

  bf16x8 qf[4];
  {
    const __bf16* Qb = Q + ((size_t)b * NN + n0 + cq) * DQ + g * 8;
#pragma unroll
    for (int kc = 0; kc < 4; ++kc) qf[kc] = *(const bf16x8*)(Qb + kc * 32);
  }

  float m[4] = {-1e30f, -1e30f, -1e30f, -1e30f};
  float l[4] = {0.f, 0.f, 0.f, 0.f};
  f32x4 h[16] = {};

  // ---- staging: LDS dest is linear (base + lane*16), K tile is contiguous,
  // V tile rows are 64B slices of the pre-transposed global Vt.
#define STAGE(c, t)                                                          \
  do {                                                                       \
    const int kv_ = kvbase + (t) * 32;                                       \
    const __bf16* ks_ = Kb + (size_t)kv_ * DQ;                               \
    _Pragma("unroll")                                                        \
    for (int j = 0; j < 2; ++j) {                                            \
      const int f = (j * 256 + tid) * 8;                                     \
      gl_lds16(ks_ + f, &Kt[c][0][0] + f);                                   \
    }                                                                        \
    _Pragma("unroll")                                                        \
    for (int j = 0; j < 4; ++j) {                                            \
      const int f = (j * 256 + tid) * 8;                                     \
      gl_lds16(Vb + (size_t)(f >> 5) * NN + kv_ + (f & 31),                  \
               &Vs[c][0][0] + f);                                            \
    }                                                                        \
  } while (0)

  STAGE(0, 0);
  __syncthreads();
  int cur = 0;

  for (int t = 0; t < nsteps; ++t) {
    if (t + 1 < nsteps) STAGE(cur ^ 1, t + 1);

    // ---- QK^T on current tile
    f32x4 s[2] = {};
#pragma unroll
    for (int kc = 0; kc < 4; ++kc) {
#pragma unroll
      for (int ct = 0; ct < 2; ++ct) {
        bf16x8 kf = *(const bf16x8*)&Kt[cur][ct * 16 + cq][kc * 32 + g * 8];
        s[ct] = __builtin_amdgcn_mfma_f32_16x16x32_bf16(qf[kc], kf, s[ct], 0, 0, 0);
      }
    }
    // ---- online softmax (rows live at reg r within 16-lane groups)
    float alpha[4];
#pragma unroll
    for (int r = 0; r < 4; ++r) {
      float mx = fmaxf(s[0][r], s[1][r]);
      mx = fmaxf(mx, __shfl_xor(mx, 1));
      mx = fmaxf(mx, __shfl_xor(mx, 2));
      mx = fmaxf(mx, __shfl_xor(mx, 4));
      mx = fmaxf(mx, __shfl_xor(mx, 8));
      const float mn = fmaxf(m[r], mx);
      alpha[r] = __expf(m[r] - mn);
      m[r] = mn;
    }
    float rs[4] = {0.f, 0.f, 0.f, 0.f};
#pragma unroll
    for (int ct = 0; ct < 2; ++ct) {
#pragma unroll
      for (int r = 0; r < 4; ++r) {
        const float p = __expf(s[ct][r] - m[r]);
        P[w][g * 4 + r][ct * 16 + cq] = (__bf16)p;
        rs[r] += p;
      }
    }
#pragma unroll
    for (int r = 0; r < 4; ++r) {
      rs[r] += __shfl_xor(rs[r], 1);
      rs[r] += __shfl_xor(rs[r], 2);
      rs[r] += __shfl_xor(rs[r], 4);
      rs[r] += __shfl_xor(rs[r], 8);
      l[r] = l[r] * alpha[r] + rs[r];
    }
#pragma unroll
    for (int et = 0; et < 16; ++et) {
#pragma unroll
      for (int r = 0; r < 4; ++r) h[et][r] *= alpha[r];
    }
    // ---- PV from LDS (P per-wave, V shared tile)
    bf16x8 pf = *(const bf16x8*)&P[w][cq][g * 8];
#pragma unroll
    for (int et = 0; et < 16; ++et) {
      bf16x8 vf = *(const bf16x8*)&Vs[cur][et * 16 + cq][g * 8];
      h[et] = __builtin_amdgcn_mfma_f32_16x16x32_bf16(pf, vf, h[et], 0, 0, 0);
    }
    __syncthreads();   // drains vmcnt (stage done) + all waves past tile reads
    cur ^= 1;
  }
#undef STAGE

  if (KSPLIT == 1) {
    float inv[4];
#pragma unroll
    for (int r = 0; r < 4; ++r) inv[r] = 1.0f / l[r];
#pragma unroll
    for (int et = 0; et < 16; ++et) {
#pragma unroll
      for (int r = 0; r < 4; ++r) {
        const int n = n0 + g * 4 + r;
        Hout[((size_t)b * NN + n) * NE + et * 16 + cq] = (__bf16)(h[et][r] * inv[r]);
      }
    }
  } else {
#pragma unroll
    for (int et = 0; et < 16; ++et) {
#pragma unroll
      for (int r = 0; r < 4; ++r) {
        const int n = n0 + g * 4 + r;
        Hout[(((size_t)split * NB + b) * NN + n) * NE + et * 16 + cq] = (__bf16)h[et][r];
      }
    }
    if (cq == 0) {
#pragma unroll
      for (int r = 0; r < 4; ++r)
        ml[((size_t)split * NB + b) * NN + n0 + g * 4 + r] = make_float2(m[r], l[r]);
    }
  }
}

// ------------------------------------------------------------- combine ------
__global__ __launch_bounds__(256) void combine_k(
    const __bf16* __restrict__ Hp, const float2* __restrict__ ml,
    __bf16* __restrict__ H)
{
  const int row = blockIdx.x * 8 + (threadIdx.x >> 5);   // flat (b,n)
  const int e0  = (threadIdx.x & 31) * 8;
  const float2 a = ml[row];
  const float2 c = ml[(size_t)NB * NN + row];
  const float M  = fmaxf(a.x, c.x);
  const float w0 = __expf(a.x - M), w1 = __expf(c.x - M);
  const float inv = 1.0f / (w0 * a.y + w1 * c.y);
  bf16x8 h0 = *(const bf16x8*)(Hp + (size_t)row * NE + e0);
  bf16x8 h1 = *(const bf16x8*)(Hp + ((size_t)NB * NN + row) * NE + e0);
  bf16x8 o;
#pragma unroll
  for (int i = 0; i < 8; ++i)
    o[i] = (__bf16)((w0 * (float)h0[i] + w1 * (float)h1[i]) * inv);
  *(bf16x8*)(H + (size_t)row * NE + e0) = o;
}

// ------------------------------------------------------------ out proj ------
__global__ __launch_bounds__(256) void outproj_k(
    const __bf16* __restrict__ H, const float* __restrict__ Wo,
    const float* __restrict__ bo, const float* __restrict__ x,
    float* __restrict__ out)
{
  const int b    = blockIdx.y;
  const int w    = threadIdx.x >> 6;
  const int lane = threadIdx.x & 63;
  const int cq   = lane & 15, g = lane >> 4;
  const int n0   = blockIdx.x * 64 + w * 16;

  f32x4 acc[16] = {};
  const __bf16* Hb = H + ((size_t)b * NN + n0 + cq) * NE;
#pragma unroll
  for (int kc = 0; kc < 8; ++kc) {
    bf16x8 af = *(const bf16x8*)(Hb + kc * 32 + g * 8);
#pragma unroll
    for (int ct = 0; ct < 16; ++ct) {
      bf16x8 bfr = pack_w(Wo + (ct * 16 + cq) * CH + kc * 32 + g * 8);
      acc[ct] = __builtin_amdgcn_mfma_f32_16x16x32_bf16(af, bfr, acc[ct], 0, 0, 0);
    }
  }
#pragma unroll
  for (int ct = 0; ct < 16; ++ct) {
    const int f = ct * 16 + cq;
    const float bias = bo[f];
#pragma unroll
    for (int r = 0; r < 4; ++r) {
      const int n = n0 + g * 4 + r;
      const size_t idx = ((size_t)b * CH + f) * NN + n;
      out[idx] = x[idx] + acc[ct][r] + bias;
    }
  }
}

// ----------------------------------------------------------------------------
extern "C" void kernel_launch(void* const* d_in, const int* in_sizes, int n_in,
                              void* d_out, int out_size, void* d_ws, size_t ws_size,
                              hipStream_t stream) {
  const float* x  = (const float*)d_in[0];
  const float* y  = (const float*)d_in[1];
  const float* Wq = (const float*)d_in[2];
  const float* bq = (const float*)d_in[3];
  const float* Wk = (const float*)d_in[4];
  const float* bk = (const float*)d_in[5];
  const float* Wv = (const float*)d_in[6];
  const float* bv = (const float*)d_in[7];
  const float* Wo = (const float*)d_in[8];
  const float* bo = (const float*)d_in[9];
  float* out = (float*)d_out;

  char* ws = (char*)d_ws;
  __bf16* Q   = (__bf16*)(ws);                            //  8 MB [b][n][128]
  __bf16* K   = (__bf16*)(ws + ((size_t)8  << 20));       //  8 MB [b][n][128]
  __bf16* Vt  = (__bf16*)(ws + ((size_t)16 << 20));       // 16 MB [b][e][n]
  __bf16* Hp  = (__bf16*)(ws + ((size_t)32 << 20));       // 32 MB partials (or 16 MB H)
  float2* ml  = (float2*)(ws + ((size_t)64 << 20));       // 512 KB (m,l) pairs
  __bf16* Hf  = (__bf16*)(ws);                            // final H over dead Q/K

  dim3 grid(64, 8), blk(256);
  proj_q_k <<<grid, blk, 0, stream>>>(y, Wq, bq, Q);
  proj_kv_k<<<grid, blk, 0, stream>>>(x, Wk, bk, Wv, bv, K, Vt);

  const size_t need = ((size_t)64 << 20) + (size_t)2 * NB * NN * sizeof(float2);
  if (ws_size >= need) {
    attn2_k<2><<<dim3(64, 8, 2), blk, 0, stream>>>(Q, K, Vt, Hp, ml);
    combine_k<<<dim3(NB * NN / 8), blk, 0, stream>>>(Hp, ml, Hf);
    outproj_k<<<grid, blk, 0, stream>>>(Hf, Wo, bo, x, out);
  } else {
    attn2_k<1><<<dim3(64, 8, 1), blk, 0, stream>>>(Q, K, Vt, Hp, nullptr);
    outproj_k<<<grid, blk, 0, stream>>>(Hp, Wo, bo, x, out);
  }
}

// Round 4
// 480.262 us; speedup vs baseline: 2.2167x; 1.3899x over previous
//
#include <hip/hip_runtime.h>
#include <hip/hip_bf16.h>
#include <stdint.h>

#define NB 8
#define CH 256
#define DQ 128
#define NE 256
#define NN 4096

using bf16x8 = __attribute__((ext_vector_type(8))) __bf16;
using bf16x4 = __attribute__((ext_vector_type(4))) __bf16;
using f32x4  = __attribute__((ext_vector_type(4))) float;

__device__ __forceinline__ void gl_lds16(const void* g, void* l){
  __builtin_amdgcn_global_load_lds(
      (const __attribute__((address_space(1))) unsigned int*)g,
      (__attribute__((address_space(3))) unsigned int*)l, 16, 0, 0);
}

// -------------------------------------------------------- weight prep -------
// convert Wq|Wk|Wv|Wo fp32 -> bf16 once; proj kernels then load bf16x8 direct.
__global__ __launch_bounds__(256) void wprep_k(
    const float* __restrict__ Wq, const float* __restrict__ Wk,
    const float* __restrict__ Wv, const float* __restrict__ Wo,
    __bf16* __restrict__ Wb)
{
  const int bidx = blockIdx.x;
  const float* s4;  __bf16* d;  int i = bidx * 256 + threadIdx.x;
  if (bidx < 32)       { s4 = Wq; d = Wb;          }
  else if (bidx < 64)  { s4 = Wk; d = Wb + 32768;  i -= 32 * 256; }
  else if (bidx < 128) { s4 = Wv; d = Wb + 65536;  i -= 64 * 256; }
  else                 { s4 = Wo; d = Wb + 131072; i -= 128 * 256; }
  float4 v = ((const float4*)s4)[i];
  bf16x4 o; o[0]=(__bf16)v.x; o[1]=(__bf16)v.y; o[2]=(__bf16)v.z; o[3]=(__bf16)v.w;
  *(bf16x4*)(d + i * 4) = o;
}

// ---------------------------------------------------------------- proj Q ----
__global__ __launch_bounds__(256) void proj_q_k(
    const float* __restrict__ y, const __bf16* __restrict__ Wqb,
    const float* __restrict__ bq, __bf16* __restrict__ Q)
{
  const int b    = blockIdx.y;
  const int w    = threadIdx.x >> 6;
  const int lane = threadIdx.x & 63;
  const int cq   = lane & 15, g = lane >> 4;
  const int n0   = blockIdx.x * 64 + w * 16;
  const float scale = 0.08838834764831845f;  // 1/sqrt(128)

  f32x4 acc[8] = {};
  const float* yb = y + (size_t)b * CH * NN;
#pragma unroll
  for (int kc = 0; kc < 8; ++kc) {
    const int kb = kc * 32 + g * 8;
    bf16x8 af;
#pragma unroll
    for (int s = 0; s < 8; ++s)
      af[s] = (__bf16)yb[(size_t)(kb + s) * NN + n0 + cq];
#pragma unroll
    for (int ct = 0; ct < 8; ++ct) {
      bf16x8 bfr = *(const bf16x8*)(Wqb + (ct * 16 + cq) * CH + kb);
      acc[ct] = __builtin_amdgcn_mfma_f32_16x16x32_bf16(af, bfr, acc[ct], 0, 0, 0);
    }
  }
#pragma unroll
  for (int ct = 0; ct < 8; ++ct) {
    const int col = ct * 16 + cq;
    const float bias = bq[col];
#pragma unroll
    for (int r = 0; r < 4; ++r) {
      const int n = n0 + g * 4 + r;
      Q[((size_t)b * NN + n) * DQ + col] = (__bf16)((acc[ct][r] + bias) * scale);
    }
  }
}

// --------------------------------------------------------------- proj KV ----
__global__ __launch_bounds__(256) void proj_kv_k(
    const float* __restrict__ x,
    const __bf16* __restrict__ Wkb, const float* __restrict__ bk,
    const __bf16* __restrict__ Wvb, const float* __restrict__ bv,
    __bf16* __restrict__ K, __bf16* __restrict__ Vt)
{
  const int b    = blockIdx.y;
  const int w    = threadIdx.x >> 6;
  const int lane = threadIdx.x & 63;
  const int cq   = lane & 15, g = lane >> 4;
  const int n0   = blockIdx.x * 64 + w * 16;

  f32x4 acc[24] = {};
  const float* xb = x + (size_t)b * CH * NN;
#pragma unroll
  for (int kc = 0; kc < 8; ++kc) {
    const int kb = kc * 32 + g * 8;
    bf16x8 af;
#pragma unroll
    for (int s = 0; s < 8; ++s)
      af[s] = (__bf16)xb[(size_t)(kb + s) * NN + n0 + cq];
#pragma unroll
    for (int ct = 0; ct < 24; ++ct) {
      const __bf16* wbase = (ct < 8) ? (Wkb + (ct * 16 + cq) * CH)
                                     : (Wvb + ((ct - 8) * 16 + cq) * CH);
      bf16x8 bfr = *(const bf16x8*)(wbase + kb);
      acc[ct] = __builtin_amdgcn_mfma_f32_16x16x32_bf16(af, bfr, acc[ct], 0, 0, 0);
    }
  }
#pragma unroll
  for (int ct = 0; ct < 8; ++ct) {
    const int col = ct * 16 + cq;
    const float bias = bk[col];
#pragma unroll
    for (int r = 0; r < 4; ++r) {
      const int n = n0 + g * 4 + r;
      K[((size_t)b * NN + n) * DQ + col] = (__bf16)(acc[ct][r] + bias);
    }
  }
#pragma unroll
  for (int ct = 8; ct < 24; ++ct) {
    const int e = (ct - 8) * 16 + cq;
    const float bias = bv[e];
#pragma unroll
    for (int r = 0; r < 4; ++r) {
      const int n = n0 + g * 4 + r;
      Vt[((size_t)b * NE + e) * NN + n] = (__bf16)(acc[ct][r] + bias);
    }
  }
}

// ------------------------------------------------------------- attention ----
// flash-style, LDS-staged K/V via global_load_lds (double buffer), all LDS
// tiles XOR-swizzled at 16B-chunk granularity (linear dest + pre-swizzled
// global source + swizzled reads). Defer-max rescale (THR=8).
template<int KSPLIT>
__global__ __launch_bounds__(256) void attn2_k(
    const __bf16* __restrict__ Q, const __bf16* __restrict__ K,
    const __bf16* __restrict__ Vt, __bf16* __restrict__ Hout,
    float2* __restrict__ ml)
{
  __shared__ __bf16 Kt[2][32][128];   // [buf][kv][d]  chunk ^= kv&15
  __shared__ __bf16 Vs[2][256][32];   // [buf][e][kv]  chunk ^= (e>>1)&3
  __shared__ __bf16 P[4][16][32];     // [wave][q][kv] chunk ^= (q>>1)&3

  const int tid  = threadIdx.x;
  const int w    = tid >> 6, lane = tid & 63;
  const int cq   = lane & 15, g = lane >> 4;
  const int b    = blockIdx.y;
  const int split = (KSPLIT == 2) ? blockIdx.z : 0;
  const int n0   = blockIdx.x * 64 + w * 16;
  const int kvbase = split * (NN / KSPLIT);
  const int nsteps = (NN / KSPLIT) / 32;

  const __bf16* Kb = K  + (size_t)b * NN * DQ;
  const __bf16* Vb = Vt + (size_t)b * NE * NN;

  bf16x8 qf[4];
  {
    const __bf16* Qb = Q + ((size_t)b * NN + n0 + cq) * DQ + g * 8;
#pragma unroll
    for (int kc = 0; kc < 4; ++kc) qf[kc] = *(const bf16x8*)(Qb + kc * 32);
  }

  float m[4] = {-1e30f, -1e30f, -1e30f, -1e30f};
  float l[4] = {0.f, 0.f, 0.f, 0.f};
  f32x4 h[16] = {};

  // linear LDS dest (base + lane*16); swizzle folded into the GLOBAL source.
#define STAGE(dst, t)                                                        \
  do {                                                                       \
    const int kv_ = kvbase + (t) * 32;                                       \
    const __bf16* ks_ = Kb + (size_t)kv_ * DQ;                               \
    _Pragma("unroll")                                                        \
    for (int j = 0; j < 2; ++j) {                                            \
      const int D = j * 256 + tid;        /* chunk idx, 512 = 32row x16 */   \
      const int row = D >> 4, c0 = D & 15;                                   \
      gl_lds16(ks_ + (size_t)row * DQ + ((c0 ^ (row & 15)) << 3),            \
               &Kt[dst][0][0] + D * 8);                                      \
    }                                                                        \
    _Pragma("unroll")                                                        \
    for (int j = 0; j < 4; ++j) {                                            \
      const int D = j * 256 + tid;        /* chunk idx, 1024 = 256row x4 */  \
      const int e = D >> 2, c0 = D & 3;                                      \
      gl_lds16(Vb + (size_t)e * NN + kv_ + ((c0 ^ ((e >> 1) & 3)) << 3),     \
               &Vs[dst][0][0] + D * 8);                                      \
    }                                                                        \
  } while (0)

  STAGE(0, 0);
  __syncthreads();
  int cur = 0;

  for (int t = 0; t < nsteps; ++t) {
    if (t + 1 < nsteps) STAGE(cur ^ 1, t + 1);

    // ---- QK^T on current tile (swizzled reads)
    f32x4 s[2] = {};
#pragma unroll
    for (int kc = 0; kc < 4; ++kc) {
#pragma unroll
      for (int ct = 0; ct < 2; ++ct) {
        bf16x8 kf = *(const bf16x8*)&Kt[cur][ct * 16 + cq][((kc * 4 + g) ^ cq) * 8];
        s[ct] = __builtin_amdgcn_mfma_f32_16x16x32_bf16(qf[kc], kf, s[ct], 0, 0, 0);
      }
    }
    // ---- online softmax with defer-max (THR=8)
    float mx[4];
#pragma unroll
    for (int r = 0; r < 4; ++r) {
      float v = fmaxf(s[0][r], s[1][r]);
      v = fmaxf(v, __shfl_xor(v, 1));
      v = fmaxf(v, __shfl_xor(v, 2));
      v = fmaxf(v, __shfl_xor(v, 4));
      v = fmaxf(v, __shfl_xor(v, 8));
      mx[r] = v;
    }
    const int need = (mx[0] > m[0] + 8.0f) | (mx[1] > m[1] + 8.0f) |
                     (mx[2] > m[2] + 8.0f) | (mx[3] > m[3] + 8.0f);
    if (__any(need)) {
      float alpha[4];
#pragma unroll
      for (int r = 0; r < 4; ++r) {
        const float mn = fmaxf(m[r], mx[r]);
        alpha[r] = __expf(m[r] - mn);
        m[r] = mn;
        l[r] *= alpha[r];
      }
#pragma unroll
      for (int et = 0; et < 16; ++et) {
#pragma unroll
        for (int r = 0; r < 4; ++r) h[et][r] *= alpha[r];
      }
    }
    float rs[4] = {0.f, 0.f, 0.f, 0.f};
#pragma unroll
    for (int ct = 0; ct < 2; ++ct) {
#pragma unroll
      for (int r = 0; r < 4; ++r) {
        const float p = __expf(s[ct][r] - m[r]);
        const int prow = g * 4 + r;
        const int c0 = ct * 2 + (cq >> 3);
        P[w][prow][((c0 ^ ((prow >> 1) & 3)) << 3) + (cq & 7)] = (__bf16)p;
        rs[r] += p;
      }
    }
#pragma unroll
    for (int r = 0; r < 4; ++r) {
      rs[r] += __shfl_xor(rs[r], 1);
      rs[r] += __shfl_xor(rs[r], 2);
      rs[r] += __shfl_xor(rs[r], 4);
      rs[r] += __shfl_xor(rs[r], 8);
      l[r] += rs[r];
    }
    // ---- PV from LDS (swizzled reads)
    bf16x8 pf = *(const bf16x8*)&P[w][cq][(g ^ ((cq >> 1) & 3)) * 8];
#pragma unroll
    for (int et = 0; et < 16; ++et) {
      bf16x8 vf = *(const bf16x8*)&Vs[cur][et * 16 + cq][(g ^ ((cq >> 1) & 3)) * 8];
      h[et] = __builtin_amdgcn_mfma_f32_16x16x32_bf16(pf, vf, h[et], 0, 0, 0);
    }
    __syncthreads();
    cur ^= 1;
  }
#undef STAGE

  if (KSPLIT == 1) {
    float inv[4];
#pragma unroll
    for (int r = 0; r < 4; ++r) inv[r] = 1.0f / l[r];
#pragma unroll
    for (int et = 0; et < 16; ++et) {
#pragma unroll
      for (int r = 0; r < 4; ++r) {
        const int n = n0 + g * 4 + r;
        Hout[((size_t)b * NN + n) * NE + et * 16 + cq] = (__bf16)(h[et][r] * inv[r]);
      }
    }
  } else {
#pragma unroll
    for (int et = 0; et < 16; ++et) {
#pragma unroll
      for (int r = 0; r < 4; ++r) {
        const int n = n0 + g * 4 + r;
        Hout[(((size_t)split * NB + b) * NN + n) * NE + et * 16 + cq] = (__bf16)h[et][r];
      }
    }
    if (cq == 0) {
#pragma unroll
      for (int r = 0; r < 4; ++r)
        ml[((size_t)split * NB + b) * NN + n0 + g * 4 + r] = make_float2(m[r], l[r]);
    }
  }
}

// ------------------------------------------------------------- combine ------
__global__ __launch_bounds__(256) void combine_k(
    const __bf16* __restrict__ Hp, const float2* __restrict__ ml,
    __bf16* __restrict__ H)
{
  const int row = blockIdx.x * 8 + (threadIdx.x >> 5);   // flat (b,n)
  const int e0  = (threadIdx.x & 31) * 8;
  const float2 a = ml[row];
  const float2 c = ml[(size_t)NB * NN + row];
  const float M  = fmaxf(a.x, c.x);
  const float w0 = __expf(a.x - M), w1 = __expf(c.x - M);
  const float inv = 1.0f / (w0 * a.y + w1 * c.y);
  bf16x8 h0 = *(const bf16x8*)(Hp + (size_t)row * NE + e0);
  bf16x8 h1 = *(const bf16x8*)(Hp + ((size_t)NB * NN + row) * NE + e0);
  bf16x8 o;
#pragma unroll
  for (int i = 0; i < 8; ++i)
    o[i] = (__bf16)((w0 * (float)h0[i] + w1 * (float)h1[i]) * inv);
  *(bf16x8*)(H + (size_t)row * NE + e0) = o;
}

// ------------------------------------------------------------ out proj ------
__global__ __launch_bounds__(256) void outproj_k(
    const __bf16* __restrict__ H, const __bf16* __restrict__ Wob,
    const float* __restrict__ bo, const float* __restrict__ x,
    float* __restrict__ out)
{
  const int b    = blockIdx.y;
  const int w    = threadIdx.x >> 6;
  const int lane = threadIdx.x & 63;
  const int cq   = lane & 15, g = lane >> 4;
  const int n0   = blockIdx.x * 64 + w * 16;

  f32x4 acc[16] = {};
  const __bf16* Hb = H + ((size_t)b * NN + n0 + cq) * NE;
#pragma unroll
  for (int kc = 0; kc < 8; ++kc) {
    bf16x8 af = *(const bf16x8*)(Hb + kc * 32 + g * 8);
#pragma unroll
    for (int ct = 0; ct < 16; ++ct) {
      bf16x8 bfr = *(const bf16x8*)(Wob + (ct * 16 + cq) * CH + kc * 32 + g * 8);
      acc[ct] = __builtin_amdgcn_mfma_f32_16x16x32_bf16(af, bfr, acc[ct], 0, 0, 0);
    }
  }
#pragma unroll
  for (int ct = 0; ct < 16; ++ct) {
    const int f = ct * 16 + cq;
    const float bias = bo[f];
#pragma unroll
    for (int r = 0; r < 4; ++r) {
      const int n = n0 + g * 4 + r;
      const size_t idx = ((size_t)b * CH + f) * NN + n;
      out[idx] = x[idx] + acc[ct][r] + bias;
    }
  }
}

// ----------------------------------------------------------------------------
extern "C" void kernel_launch(void* const* d_in, const int* in_sizes, int n_in,
                              void* d_out, int out_size, void* d_ws, size_t ws_size,
                              hipStream_t stream) {
  const float* x  = (const float*)d_in[0];
  const float* y  = (const float*)d_in[1];
  const float* Wq = (const float*)d_in[2];
  const float* bq = (const float*)d_in[3];
  const float* Wk = (const float*)d_in[4];
  const float* bk = (const float*)d_in[5];
  const float* Wv = (const float*)d_in[6];
  const float* bv = (const float*)d_in[7];
  const float* Wo = (const float*)d_in[8];
  const float* bo = (const float*)d_in[9];
  float* out = (float*)d_out;

  char* ws = (char*)d_ws;
  __bf16* Wb  = (__bf16*)(ws);                            // 384 KB bf16 weights
  const size_t W_BYTES = (size_t)393216;                  // 196608 bf16
  __bf16* Q   = (__bf16*)(ws + W_BYTES);                  //  8 MB [b][n][128]
  __bf16* K   = (__bf16*)(ws + W_BYTES + ((size_t)8  << 20));
  __bf16* Vt  = (__bf16*)(ws + W_BYTES + ((size_t)16 << 20));
  __bf16* Hp  = (__bf16*)(ws + W_BYTES + ((size_t)32 << 20));
  float2* ml  = (float2*)(ws + W_BYTES + ((size_t)64 << 20));
  __bf16* Hf  = Q;                                        // final H over dead Q/K
  __bf16* Wqb = Wb, *Wkb = Wb + 32768, *Wvb = Wb + 65536, *Wob = Wb + 131072;

  dim3 grid(64, 8), blk(256);
  wprep_k  <<<dim3(192), blk, 0, stream>>>(Wq, Wk, Wv, Wo, Wb);
  proj_q_k <<<grid, blk, 0, stream>>>(y, Wqb, bq, Q);
  proj_kv_k<<<grid, blk, 0, stream>>>(x, Wkb, bk, Wvb, bv, K, Vt);

  const size_t need = W_BYTES + ((size_t)64 << 20)
                    + (size_t)2 * NB * NN * sizeof(float2);
  if (ws_size >= need) {
    attn2_k<2><<<dim3(64, 8, 2), blk, 0, stream>>>(Q, K, Vt, Hp, ml);
    combine_k<<<dim3(NB * NN / 8), blk, 0, stream>>>(Hp, ml, Hf);
    outproj_k<<<grid, blk, 0, stream>>>(Hf, Wob, bo, x, out);
  } else {
    attn2_k<1><<<dim3(64, 8, 1), blk, 0, stream>>>(Q, K, Vt, Hp, nullptr);
    outproj_k<<<grid, blk, 0, stream>>>(Hp, Wob, bo, x, out);
  }
}